// Round 15
// baseline (16.209 us; speedup 1.0000x reference)
//
#include <hip/hip_runtime.h>

// BSEC_RNN: B=4096, T=2048, I=1, H=2, O=1.
//   h[t] = tanh(W_ih*x[t] + b_ih + b_hh + W_hh @ h[t-1]),  h[-1] = 0
//   out[t] = fc_w[0]*x[t] + fc_w[1]*h0[t] + fc_w[2]*h1[t] + fc_b
//
// r15 = r14 (best: 4 waves x [64 seqs, 4 chunks], WARM=16, b128-swizzled
// LDS, two barriers, 4 blocks/CU = 16 waves/CU, XCD-bijective remap)
// + DISPATCH-ROUND STAGGER: blocks in odd dispatch rounds (blockIdx>>8 & 1;
// each CU receives one block per 256-block round, so 2 of its 4 resident
// blocks sleep) spin ~2.1us before staging. Breaks the chip-wide phase
// lockstep (stage|compute|store self-synchronize via HBM contention):
// runners compute while sleepers stage, store while sleepers compute ->
// HBM never idles during the compute phase. Zero extra fetch, zero lost
// waves, arithmetic bit-identical to r14.
//
// LDS layout (validated r14): group q, seq r -> lx[q*256 + ((r^q)&63)*4],
// 4 contiguous words x[4q..4q+3]; one ds_read_b128/ds_write_b128 per access,
// conflict-free (8 consecutive lanes -> 8 distinct 16B bank-groups).
// Math (validated r6-r14): rr=(r0,r1), r = 1/(1+exp2(p)), h = 1-2r folded
// into coefficients; v_pk_fma_f32 op_sel broadcasts.

typedef float f32x2 __attribute__((ext_vector_type(2)));
typedef float f32x4 __attribute__((ext_vector_type(4)));

constexpr int T_LEN   = 2048;
constexpr int CHUNK   = 32;
constexpr int WARM    = 16;
constexpr int THREADS = 256;
constexpr int OSPAN   = 128;               // 4 chunks * 32
constexpr int SPAN    = OSPAN + WARM;      // 144 floats/seq staged (cg>0)
constexpr int NCG     = T_LEN / OSPAN;     // 16 chunk-groups
constexpr int NGRP    = SPAN / 4;          // 36 f4-groups

static __device__ inline float EXP2F(float x){ float r; asm("v_exp_f32 %0, %1":"=v"(r):"v"(x)); return r; }
static __device__ inline float RCPF(float x){ float r; asm("v_rcp_f32 %0, %1":"=v"(r):"v"(x)); return r; }
static __device__ inline f32x2 mk2(float a, float b){ f32x2 t; t.x=a; t.y=b; return t; }

#define PK_FMA_B0(d, s0, s1, s2)                                          \
    asm("v_pk_fma_f32 %0, %1, %2, %3 op_sel:[0,0,0] op_sel_hi:[0,1,1]"    \
        : "=v"(d) : "v"(s0), "v"(s1), "v"(s2))
#define PK_FMA_B1(d, s0, s1, s2)                                          \
    asm("v_pk_fma_f32 %0, %1, %2, %3 op_sel:[1,0,0] op_sel_hi:[1,1,1]"    \
        : "=v"(d) : "v"(s0), "v"(s1), "v"(s2))
#define PK_ADD(d, s0, s1)                                                 \
    asm("v_pk_add_f32 %0, %1, %2" : "=v"(d) : "v"(s0), "v"(s1))

#define PSTEP_CORE(bb)                                                    \
    do {                                                                  \
        f32x2 q_, p_, e_, d_;                                             \
        PK_FMA_B1(q_, rr, mm1, (bb));                                     \
        PK_FMA_B0(p_, rr, mm0, q_);                                       \
        e_.x = EXP2F(p_.x); e_.y = EXP2F(p_.y);                           \
        PK_ADD(d_, e_, ones);                                             \
        rr.x = RCPF(d_.x); rr.y = RCPF(d_.y);                             \
    } while (0)

#define WSTEP_LO(xp2) do { f32x2 b_; PK_FMA_B0(b_, (xp2), aa, cc); PSTEP_CORE(b_); } while (0)
#define WSTEP_HI(xp2) do { f32x2 b_; PK_FMA_B1(b_, (xp2), aa, cc); PSTEP_CORE(b_); } while (0)
#define OSTEP_LO(xp2, ok) do { WSTEP_LO(xp2); (ok) = fmaf(rr.y, g2, fmaf(rr.x, g1, fmaf((xp2).x, f0, fb))); } while (0)
#define OSTEP_HI(xp2, ok) do { WSTEP_HI(xp2); (ok) = fmaf(rr.y, g2, fmaf(rr.x, g1, fmaf((xp2).y, f0, fb))); } while (0)

// One 4-step group from a b128 LDS read (v = x[4q..4q+3]).
#define WG4()                                                             \
    do {                                                                  \
        f32x4 v = *(const f32x4*)&lx[q * 256 + (((l ^ q) & 63) << 2)];    \
        f32x2 xa_ = mk2(v.x, v.y), xb_ = mk2(v.z, v.w);                   \
        WSTEP_LO(xa_); WSTEP_HI(xa_); WSTEP_LO(xb_); WSTEP_HI(xb_);       \
        ++q;                                                              \
    } while (0)

#define OQ(oo)                                                            \
    do {                                                                  \
        f32x4 v = *(const f32x4*)&lx[q * 256 + (((l ^ q) & 63) << 2)];    \
        f32x2 xa_ = mk2(v.x, v.y), xb_ = mk2(v.z, v.w);                   \
        OSTEP_LO(xa_, oo.x); OSTEP_HI(xa_, oo.y);                         \
        OSTEP_LO(xb_, oo.z); OSTEP_HI(xb_, oo.w);                         \
        ++q;                                                              \
    } while (0)

__global__ __launch_bounds__(THREADS, 4) void rnn_stg(
    const float* __restrict__ x,
    const float* __restrict__ W_ih,
    const float* __restrict__ W_hh,
    const float* __restrict__ b_ih,
    const float* __restrict__ b_hh,
    const float* __restrict__ fc_w,
    const float* __restrict__ fc_b,
    float* __restrict__ out)
{
    __shared__ float lx[NGRP * 256];      // 36 KB

    // Dispatch-round stagger: each CU hosts one block per 256-block round;
    // odd-round blocks sleep ~2.1us so runner blocks' compute phase is
    // covered by sleeper blocks' stage phase (and stores by computes).
    if ((blockIdx.x >> 8) & 1) {
        #pragma unroll
        for (int i = 0; i < 10; ++i) __builtin_amdgcn_s_sleep(8);
    }

    // XCD-bijective remap (grid 1024 = 8 XCDs * 128): consecutive lb
    // (same sg, consecutive cg) land on one XCD -> warm-overlap L2 hits.
    const int lb  = ((blockIdx.x & 7) << 7) | (blockIdx.x >> 3);
    const int sg  = lb >> 4;              // sequence group (64 seqs)
    const int cg  = lb & (NCG - 1);       // chunk-group
    const int tid = threadIdx.x;
    const int w   = tid >> 6, l = tid & 63;

    const int tlo = cg ? cg * OSPAN - WARM : 0;
    const float* xg = x + (size_t)(sg * 64) * T_LEN + tlo;

    // ---- Stage x: coalesced global f32x4 -> b128-swizzled LDS ----
    if (cg != 0) {
        // 36 f4-cols x 64 seq-rows = 2304 f4, 9 per thread
        #pragma unroll
        for (int k = 0; k < 9; ++k) {
            int idx = k * THREADS + tid;
            int r_ = idx / NGRP, c_ = idx - r_ * NGRP;
            f32x4 v = *(const f32x4*)(xg + (size_t)r_ * T_LEN + (c_ << 2));
            *(f32x4*)&lx[c_ * 256 + (((r_ ^ c_) & 63) << 2)] = v;
        }
    } else {
        // 32 f4-cols x 64 rows = 2048 f4, 8 per thread
        #pragma unroll
        for (int k = 0; k < 8; ++k) {
            int idx = k * THREADS + tid;
            int r_ = idx >> 5, c_ = idx & 31;
            f32x4 v = *(const f32x4*)(xg + (size_t)r_ * T_LEN + (c_ << 2));
            *(f32x4*)&lx[c_ * 256 + (((r_ ^ c_) & 63) << 2)] = v;
        }
    }

    // ---- Coefficients (r-trick folding, s = 2*log2(e)) ----
    const float s2 = 2.0f * 1.44269504088896340736f;
    const float W00 = W_hh[0], W01 = W_hh[1], W10 = W_hh[2], W11 = W_hh[3];
    const f32x2 aa  = mk2(W_ih[0] * s2, W_ih[1] * s2);
    const f32x2 cc  = mk2((b_ih[0] + b_hh[0] + W00 + W01) * s2,
                          (b_ih[1] + b_hh[1] + W10 + W11) * s2);
    const f32x2 mm0 = mk2(-2.0f * s2 * W00, -2.0f * s2 * W10);
    const f32x2 mm1 = mk2(-2.0f * s2 * W01, -2.0f * s2 * W11);
    const f32x2 ones = mk2(1.0f, 1.0f);
    const float f0 = fc_w[0];
    const float g1 = -2.0f * fc_w[1], g2 = -2.0f * fc_w[2];
    const float fb = fc_b[0] + fc_w[1] + fc_w[2];

    __syncthreads();                      // bar1: full span staged

    // ---- Compute: wave w = chunk cg*4+w, lane = seq ----
    f32x4 o0, o1, o2, o3, o4, o5, o6, o7;
    {
        int q, warm_q;
        if (cg == 0) {
            int gt = w * CHUNK - WARM; if (gt < 0) gt = 0;
            q = gt >> 2; warm_q = (w * CHUNK - gt) >> 2;   // w0:0, else 4
        } else {
            q = w * 8; warm_q = WARM >> 2;                 // 4
        }
        f32x2 rr = mk2(0.5f, 0.5f);       // h = 0
        #pragma unroll
        for (int i = 0; i < warm_q; ++i) { WG4(); }
        OQ(o0); OQ(o1); OQ(o2); OQ(o3); OQ(o4); OQ(o5); OQ(o6); OQ(o7);
    }

    __syncthreads();                      // bar2: all x reads done

    // ---- OWR into slots [w*8, w*8+8) (post-bar2: no readers remain),
    //      same-wave b128 readback, coalesced NT store ----
    #pragma unroll
    for (int j = 0; j < 8; ++j) {
        f32x4 oo = (j==0)?o0:(j==1)?o1:(j==2)?o2:(j==3)?o3:
                   (j==4)?o4:(j==5)?o5:(j==6)?o6:o7;
        int qo = w * 8 + j;
        *(f32x4*)&lx[qo * 256 + (((l ^ qo) & 63) << 2)] = oo;
    }
    float* og = out + (size_t)(sg * 64) * T_LEN + cg * OSPAN;
    #pragma unroll
    for (int k = 0; k < 8; ++k) {
        int idx = k * 64 + l;
        int r_ = idx >> 3;
        int c_ = w * 8 + (idx & 7);       // f4-col within block == LDS group
        f32x4 v_ = *(const f32x4*)&lx[c_ * 256 + (((r_ ^ c_) & 63) << 2)];
        __builtin_nontemporal_store(v_,
            (f32x4*)(og + (size_t)r_ * T_LEN + (c_ << 2)));
    }
}

extern "C" void kernel_launch(void* const* d_in, const int* in_sizes, int n_in,
                              void* d_out, int out_size, void* d_ws, size_t ws_size,
                              hipStream_t stream) {
    const float* x    = (const float*)d_in[0];
    const float* W_ih = (const float*)d_in[1];
    const float* W_hh = (const float*)d_in[2];
    const float* b_ih = (const float*)d_in[3];
    const float* b_hh = (const float*)d_in[4];
    const float* fc_w = (const float*)d_in[5];
    const float* fc_b = (const float*)d_in[6];
    float* out = (float*)d_out;

    const int B = in_sizes[0] / T_LEN;    // I == 1

    dim3 block(THREADS);
    dim3 grid((B / 64) * NCG);            // 1024 blocks = 4/CU
    rnn_stg<<<grid, block, 0, stream>>>(x, W_ih, W_hh, b_ih, b_hh,
                                        fc_w, fc_b, out);
}